// Round 10
// baseline (290.900 us; speedup 1.0000x reference)
//
#include <hip/hip_runtime.h>
#include <stdint.h>

#define Ttok 1024
#define Hdim 2048
#define Idim 1024
#define Enum 16
#define NKH  64
#define NKO  32

typedef __attribute__((ext_vector_type(8))) short  short8;
typedef __attribute__((ext_vector_type(4))) float  f32x4;

// barrier WITHOUT vmcnt drain: LDS ops complete, global loads stay in flight
#define BAR()  asm volatile("s_waitcnt lgkmcnt(0)\n\ts_barrier" ::: "memory")
#define SBAR() __builtin_amdgcn_sched_barrier(0)

__device__ __forceinline__ unsigned short f2bf(float f) {
    union { float f; uint32_t u; } v; v.f = f;
    uint32_t u = v.u;
    return (unsigned short)((u + 0x7FFFu + ((u >> 16) & 1u)) >> 16);
}
__device__ __forceinline__ float bf2f(unsigned short h) {
    union { uint32_t u; float f; } v; v.u = ((uint32_t)h) << 16; return v.f;
}
__device__ __forceinline__ uint32_t cvtpk(float lo, float hi) {
    uint32_t d;
    asm("v_cvt_pk_bf16_f32 %0, %1, %2" : "=v"(d) : "v"(lo), "v"(hi));
    return d;
}
__device__ __forceinline__ float silu_mul(unsigned short h1u, unsigned short h3u) {
    float h1 = bf2f(h1u), h3 = bf2f(h3u);
    return h1 * h3 * __builtin_amdgcn_rcpf(1.f + __expf(-h1));
}

// ---------------- Router ----------------
__global__ __launch_bounds__(256) void k_router(
    const float* __restrict__ x, const float* __restrict__ gw,
    const float* __restrict__ bias,
    int* __restrict__ counts, int* __restrict__ tids, float* __restrict__ tws)
{
    __shared__ __align__(16) float xrow[Hdim];
    __shared__ float lg[Enum];
    const int t = blockIdx.x;
    const float* xr = x + (size_t)t * Hdim;

    for (int i = threadIdx.x; i < Hdim / 4; i += 256)
        ((f32x4*)xrow)[i] = ((const f32x4*)xr)[i];
    __syncthreads();

    const int lane = threadIdx.x & 63;
    const int wid  = threadIdx.x >> 6;
    for (int e = wid; e < Enum; e += 4) {
        const float* g = gw + (size_t)e * Hdim;
        float s = 0.f;
        for (int j = lane; j < Hdim; j += 64) s += xrow[j] * g[j];
        #pragma unroll
        for (int off = 32; off; off >>= 1) s += __shfl_xor(s, off);
        if (lane == 0) lg[e] = s;
    }
    __syncthreads();

    if (threadIdx.x == 0) {
        float m = lg[0];
        #pragma unroll
        for (int e = 1; e < Enum; ++e) m = fmaxf(m, lg[e]);
        float sc[Enum]; float sum = 0.f;
        #pragma unroll
        for (int e = 0; e < Enum; ++e) { float ex = expf(lg[e] - m); sc[e] = ex; sum += ex; }
        float inv = 1.f / sum;
        #pragma unroll
        for (int e = 0; e < Enum; ++e) sc[e] *= inv;
        int i0 = 0; float b0 = sc[0] + bias[0];
        #pragma unroll
        for (int e = 1; e < Enum; ++e) { float bb = sc[e] + bias[e]; if (bb > b0) { b0 = bb; i0 = e; } }
        int i1 = -1; float b1 = -1e30f;
        #pragma unroll
        for (int e = 0; e < Enum; ++e) {
            if (e == i0) continue;
            float bb = sc[e] + bias[e]; if (bb > b1) { b1 = bb; i1 = e; }
        }
        float w0 = sc[i0], w1v = sc[i1];
        float winv = 1.f / (w0 + w1v);
        w0 *= winv; w1v *= winv;
        int p0 = atomicAdd(&counts[i0], 1);
        tids[i0 * Ttok + p0] = t; tws[i0 * Ttok + p0] = w0;
        int p1 = atomicAdd(&counts[i1], 1);
        tids[i1 * Ttok + p1] = t; tws[i1 * Ttok + p1] = w1v;
    }
}

// ---------------- Gather: compact + bf16 + tile X ----------------
// Xg layout: [pc*256 + kg][row 0..63][8]; pad rows zeroed. grid (8, 48).
__global__ __launch_bounds__(256) void k_gather(
    const float* __restrict__ x, const int* __restrict__ counts,
    const int* __restrict__ tids, unsigned short* __restrict__ Xg)
{
    const int p = blockIdx.y;
    int pe = -1, c = 0, acc = 0;
    #pragma unroll
    for (int j = 0; j < Enum; ++j) {
        int nj = (counts[j] + 63) >> 6;
        if (pe < 0 && p < acc + nj) { pe = j; c = p - acc; }
        acc += nj;
    }
    if (pe < 0) return;
    const int Ne = counts[pe];
    const int s  = blockIdx.x;
    const int r  = threadIdx.x & 63;
    const int kq = threadIdx.x >> 6;
    const int row = c * 64 + r;
    const bool valid = row < Ne;
    const int tok = valid ? tids[pe * Ttok + row] : 0;
    const float* xr = x + (size_t)tok * Hdim;

    #pragma unroll
    for (int j = 0; j < 8; ++j) {
        int kg = s * 32 + j * 4 + kq;
        uint4 o = make_uint4(0, 0, 0, 0);
        if (valid) {
            f32x4 p0 = *(const f32x4*)(xr + kg * 8);
            f32x4 p1 = *(const f32x4*)(xr + kg * 8 + 4);
            o.x = cvtpk(p0[0], p0[1]); o.y = cvtpk(p0[2], p0[3]);
            o.z = cvtpk(p1[0], p1[1]); o.w = cvtpk(p1[2], p1[3]);
        }
        *(uint4*)(Xg + ((size_t)(p * 256 + kg) * 64 + r) * 8) = o;
    }
}

// ---------------- Stage 2: H{1,3} = X @ W{1,3}, M=192 N=128, byte-minimal ----------------
// grid (16 = cb8 x mat2, 2 rb, 16 e), block 512 (8 waves: wr = wid>>2, wc = wid&3).
__global__ __launch_bounds__(512, 2) void k_h(
    const unsigned short* __restrict__ Xg,
    const float* __restrict__ w1, const float* __restrict__ w3,
    const int* __restrict__ counts,
    unsigned short* __restrict__ H1, unsigned short* __restrict__ H3)
{
    const int e  = blockIdx.z;
    const int Ne = counts[e];
    const int rb = blockIdx.y;
    if (rb * 192 >= Ne) return;     // rb=1 only for Ne>192 (~never)
    int poff = 0;
    #pragma unroll
    for (int j = 0; j < Enum; ++j) if (j < e) poff += (counts[j] + 63) >> 6;
    const int NC   = (Ne + 63) >> 6;
    const int mat  = blockIdx.x >> 3;
    const int cb   = blockIdx.x & 7;
    const int col0 = cb * 128;
    const int tid  = threadIdx.x;
    const int lane = tid & 63;
    const int wid  = tid >> 6;
    const int l15  = lane & 15;
    const int kq   = lane >> 4;
    const int wr   = wid >> 2, wc = wid & 3;

    __shared__ __align__(16) unsigned short Ws[2][4096];  // 16 KB: [buf][(g*128+c)*8+j]

    // W pointer: thread (c = tid&127, g = tid>>7); k-row = s*32 + g*8 + j
    const int cW = tid & 127, gW = tid >> 7;
    const float* wp = (mat ? w3 : w1) + ((size_t)e * Hdim + gW * 8) * Idim + col0 + cW;

    // A pointers per fr (rows wr*96 + fr*16 + l15), tiled Xg = fragment layout
    const unsigned short* aptr[6];
    int chValid[6];
    #pragma unroll
    for (int fr = 0; fr < 6; ++fr) {
        int row = wr * 96 + fr * 16 + l15;
        int cgl = rb * 3 + (row >> 6);           // uniform per (wave,fr)
        chValid[fr] = (cgl < NC);
        int cc = chValid[fr] ? cgl : NC - 1;
        aptr[fr] = Xg + (((size_t)(poff + cc) * 256 + kq) * 64 + (row & 63)) * 8;
    }

    f32x4 acc[6][2];
    #pragma unroll
    for (int a = 0; a < 6; ++a) { acc[a][0] = (f32x4)(0.f); acc[a][1] = (f32x4)(0.f); }

    float w0r[8], w1r[8], w2r[8], w3r[8];
    short8 aA[6], aB[6];

    auto WLOAD = [&](int s, float* d) {
        s = s < NKH ? s : NKH - 1;
        const float* p = wp + (size_t)s * 32 * Idim;
        #pragma unroll
        for (int j = 0; j < 8; ++j) d[j] = p[(size_t)j * Idim];
    };
    auto ALOAD = [&](int s, short8* d) {
        s = s < NKH ? s : NKH - 1;
        #pragma unroll
        for (int fr = 0; fr < 6; ++fr) d[fr] = *(const short8*)(aptr[fr] + (size_t)s * 2048);
    };
    auto WSTAGE = [&](int buf, const float* w) {
        uint4 q;
        q.x = cvtpk(w[0], w[1]); q.y = cvtpk(w[2], w[3]);
        q.z = cvtpk(w[4], w[5]); q.w = cvtpk(w[6], w[7]);
        *(uint4*)&Ws[buf][(gW * 128 + cW) * 8] = q;
    };
    auto MFMA = [&](int buf, const short8* a) {
        short8 b0 = *(const short8*)&Ws[buf][(kq * 128 + wc * 32 + l15) * 8];
        short8 b1 = *(const short8*)&Ws[buf][(kq * 128 + wc * 32 + 16 + l15) * 8];
        #pragma unroll
        for (int fr = 0; fr < 6; ++fr) {
            acc[fr][0] = __builtin_amdgcn_mfma_f32_16x16x32_bf16(a[fr], b0, acc[fr][0], 0, 0, 0);
            acc[fr][1] = __builtin_amdgcn_mfma_f32_16x16x32_bf16(a[fr], b1, acc[fr][1], 0, 0, 0);
        }
    };

    // prologue
    WLOAD(0, w0r); WLOAD(1, w1r); WLOAD(2, w2r);
    ALOAD(0, aA);
    SBAR();
    WSTAGE(0, w0r);
    BAR();

    for (int ks = 0; ks < NKH; ks += 4) {
        ALOAD(ks + 1, aB); SBAR();
        WLOAD(ks + 3, w3r); SBAR();
        MFMA(0, aA);
        WSTAGE(1, w1r); SBAR();
        BAR();

        ALOAD(ks + 2, aA); SBAR();
        WLOAD(ks + 4, w0r); SBAR();
        MFMA(1, aB);
        WSTAGE(0, w2r); SBAR();
        BAR();

        ALOAD(ks + 3, aB); SBAR();
        WLOAD(ks + 5, w1r); SBAR();
        MFMA(0, aA);
        WSTAGE(1, w3r); SBAR();
        BAR();

        ALOAD(ks + 4, aA); SBAR();
        WLOAD(ks + 6, w2r); SBAR();
        MFMA(1, aB);
        WSTAGE(0, w0r); SBAR();
        BAR();
    }

    // epilogue: direct global stores into tiled H [pc][KG 128][64][8]
    unsigned short* Hm = mat ? H3 : H1;
    #pragma unroll
    for (int fr = 0; fr < 6; ++fr) {
        if (chValid[fr]) {
            int row = wr * 96 + fr * 16 + l15;
            int cc  = rb * 3 + (row >> 6);
            size_t chbase = (size_t)(poff + cc) * 128;
            int rb0 = ((wr * 96 + fr * 16) & 63) + kq * 4;
            #pragma unroll
            for (int fc = 0; fc < 2; ++fc) {
                int colg = col0 + wc * 32 + fc * 16 + l15;
                size_t kgbase = (chbase + (colg >> 3)) * 512 + (colg & 7);
                #pragma unroll
                for (int k = 0; k < 4; ++k)
                    Hm[kgbase + (size_t)(rb0 + k) * 8] = f2bf(acc[fr][fc][k]);
            }
        }
    }
}

// ---------------- Stage 3: out += w * (silu(H1)*H3 @ W2), M=192 N=128 ----------------
// grid (16 cb, 2 rb, 16 e), block 512.
__global__ __launch_bounds__(512, 2) void k_o(
    const unsigned short* __restrict__ H1, const unsigned short* __restrict__ H3,
    const float* __restrict__ w2,
    const int* __restrict__ counts, const int* __restrict__ tids,
    const float* __restrict__ tws,
    float* __restrict__ out)
{
    const int e  = blockIdx.z;
    const int Ne = counts[e];
    const int rb = blockIdx.y;
    if (rb * 192 >= Ne) return;
    int poff = 0;
    #pragma unroll
    for (int j = 0; j < Enum; ++j) if (j < e) poff += (counts[j] + 63) >> 6;
    const int NC   = (Ne + 63) >> 6;
    const int col0 = blockIdx.x * 128;
    const int tid  = threadIdx.x;
    const int lane = tid & 63;
    const int wid  = tid >> 6;
    const int l15  = lane & 15;
    const int kq   = lane >> 4;
    const int wr   = wid >> 2, wc = wid & 3;

    __shared__ __align__(16) unsigned short Ws[2][4096];  // 16 KB
    __shared__ __align__(16) unsigned short As[2][6144];  // 24 KB: [buf][(g*192+row)*8]

    const int cW = tid & 127, gW = tid >> 7;
    const float* wp = w2 + ((size_t)e * Idim + gW * 8) * Hdim + col0 + cW;

    // He-stage slots: slot0 = tid, slot1 = tid+512 (tid<256)
    const unsigned short* hp1[2]; const unsigned short* hp3[2];
    int slotOff[2]; bool slotOn[2];
    #pragma unroll
    for (int q = 0; q < 2; ++q) {
        int slot = (q == 0) ? tid : (tid < 256 ? tid + 512 : tid);
        slotOn[q]  = (q == 0) || (tid < 256);
        int gs  = slot / 192;
        int row = slot - gs * 192;
        int cgl = rb * 3 + (row >> 6);
        int cc  = cgl < NC ? cgl : NC - 1;
        size_t base = (((size_t)(poff + cc) * 128 + gs) * 64 + (row & 63)) * 8;
        hp1[q] = H1 + base; hp3[q] = H3 + base;
        slotOff[q] = slot * 8;
    }

    f32x4 acc[6][2];
    #pragma unroll
    for (int a = 0; a < 6; ++a) { acc[a][0] = (f32x4)(0.f); acc[a][1] = (f32x4)(0.f); }

    float w0r[8], w1r[8], w2r[8], w3r[8];
    short8 hA[4], hB[4];   // {h1 s0, h3 s0, h1 s1, h3 s1}

    auto WLOAD = [&](int s, float* d) {
        s = s < NKO ? s : NKO - 1;
        const float* p = wp + (size_t)s * 32 * Hdim;
        #pragma unroll
        for (int j = 0; j < 8; ++j) d[j] = p[(size_t)j * Hdim];
    };
    auto HLOAD = [&](int s, short8* d) {
        s = s < NKO ? s : NKO - 1;
        d[0] = *(const short8*)(hp1[0] + (size_t)s * 2048);
        d[1] = *(const short8*)(hp3[0] + (size_t)s * 2048);
        d[2] = *(const short8*)(hp1[1] + (size_t)s * 2048);
        d[3] = *(const short8*)(hp3[1] + (size_t)s * 2048);
    };
    auto STAGE = [&](int buf, const short8* h, const float* w) {
        #pragma unroll
        for (int q = 0; q < 2; ++q) {
            if (slotOn[q]) {
                uint4 o;
                o.x = cvtpk(silu_mul(h[q*2][0], h[q*2+1][0]), silu_mul(h[q*2][1], h[q*2+1][1]));
                o.y = cvtpk(silu_mul(h[q*2][2], h[q*2+1][2]), silu_mul(h[q*2][3], h[q*2+1][3]));
                o.z = cvtpk(silu_mul(h[q*2][4], h[q*2+1][4]), silu_mul(h[q*2][5], h[q*2+1][5]));
                o.w = cvtpk(silu_mul(h[q*2][6], h[q*2+1][6]), silu_mul(h[q*2][7], h[q*2+1][7]));
                *(uint4*)&As[buf][slotOff[q]] = o;
            }
        }
        uint4 qw;
        qw.x = cvtpk(w[0], w[1]); qw.y = cvtpk(w[2], w[3]);
        qw.z = cvtpk(w[4], w[5]); qw.w = cvtpk(w[6], w[7]);
        *(uint4*)&Ws[buf][(gW * 128 + cW) * 8] = qw;
    };
    auto MFMA = [&](int buf) {
        short8 b0 = *(const short8*)&Ws[buf][(kq * 128 + wc * 32 + l15) * 8];
        short8 b1 = *(const short8*)&Ws[buf][(kq * 128 + wc * 32 + 16 + l15) * 8];
        #pragma unroll
        for (int fr = 0; fr < 6; ++fr) {
            short8 af = *(const short8*)&As[buf][(kq * 192 + wr * 96 + fr * 16 + l15) * 8];
            acc[fr][0] = __builtin_amdgcn_mfma_f32_16x16x32_bf16(af, b0, acc[fr][0], 0, 0, 0);
            acc[fr][1] = __builtin_amdgcn_mfma_f32_16x16x32_bf16(af, b1, acc[fr][1], 0, 0, 0);
        }
    };

    // prologue
    WLOAD(0, w0r); WLOAD(1, w1r); WLOAD(2, w2r);
    HLOAD(0, hA); HLOAD(1, hB);
    SBAR();
    STAGE(0, hA, w0r);
    BAR();

    for (int ks = 0; ks < NKO; ks += 4) {
        HLOAD(ks + 2, hA); SBAR();
        WLOAD(ks + 3, w3r); SBAR();
        MFMA(0);
        STAGE(1, hB, w1r); SBAR();
        BAR();

        HLOAD(ks + 3, hB); SBAR();
        WLOAD(ks + 4, w0r); SBAR();
        MFMA(1);
        STAGE(0, hA, w2r); SBAR();
        BAR();

        HLOAD(ks + 4, hA); SBAR();
        WLOAD(ks + 5, w1r); SBAR();
        MFMA(0);
        STAGE(1, hB, w3r); SBAR();
        BAR();

        HLOAD(ks + 5, hB); SBAR();
        WLOAD(ks + 6, w2r); SBAR();
        MFMA(1);
        STAGE(0, hA, w0r); SBAR();
        BAR();
    }

    #pragma unroll
    for (int fr = 0; fr < 6; ++fr) {
        #pragma unroll
        for (int k = 0; k < 4; ++k) {
            int grow = rb * 192 + wr * 96 + fr * 16 + kq * 4 + k;
            if (grow < Ne) {
                int   tk = tids[e * Ttok + grow];
                float w  = tws[e * Ttok + grow];
                #pragma unroll
                for (int fc = 0; fc < 2; ++fc)
                    atomicAdd(&out[(size_t)tk * Hdim + col0 + wc * 32 + fc * 16 + l15],
                              w * acc[fr][fc][k]);
            }
        }
    }
}

extern "C" void kernel_launch(void* const* d_in, const int* in_sizes, int n_in,
                              void* d_out, int out_size, void* d_ws, size_t ws_size,
                              hipStream_t stream)
{
    const float* x    = (const float*)d_in[0];
    const float* gw   = (const float*)d_in[1];
    const float* bias = (const float*)d_in[2];
    const float* w1   = (const float*)d_in[3];
    const float* w3   = (const float*)d_in[4];
    const float* w2   = (const float*)d_in[5];
    float* out = (float*)d_out;

    char* ws = (char*)d_ws;
    int*            counts = (int*)ws;                         // @0        64 B
    int*            tids   = (int*)(ws + 1024);                // @1K      64 KB
    float*          tws    = (float*)(ws + 66560);             // @65K     64 KB
    unsigned short* Xg     = (unsigned short*)(ws + 132096);   // 12.58 MB (48 chunks)
    unsigned short* H1     = (unsigned short*)(ws + 12715008); // 6.29 MB
    unsigned short* H3     = (unsigned short*)(ws + 19006464); // 6.29 MB -> end ~25.3 MB

    hipMemsetAsync(counts, 0, Enum * sizeof(int), stream);
    hipMemsetAsync(out, 0, (size_t)Ttok * Hdim * sizeof(float), stream);

    k_router<<<dim3(Ttok), dim3(256), 0, stream>>>(x, gw, bias, counts, tids, tws);
    k_gather<<<dim3(8, 48), dim3(256), 0, stream>>>(x, counts, tids, Xg);
    k_h<<<dim3(16, 2, Enum), dim3(512), 0, stream>>>(Xg, w1, w3, counts, H1, H3);
    k_o<<<dim3(16, 2, Enum), dim3(512), 0, stream>>>(H1, H3, w2, counts, tids, tws, out);
}

// Round 11
// 216.287 us; speedup vs baseline: 1.3450x; 1.3450x over previous
//
#include <hip/hip_runtime.h>
#include <stdint.h>

#define Ttok 1024
#define Hdim 2048
#define Idim 1024
#define Enum 16
#define NKH  64
#define NKO  32

typedef __attribute__((ext_vector_type(8))) short  short8;
typedef __attribute__((ext_vector_type(4))) float  f32x4;

__device__ __forceinline__ unsigned short f2bf(float f) {
    union { float f; uint32_t u; } v; v.f = f;
    uint32_t u = v.u;
    return (unsigned short)((u + 0x7FFFu + ((u >> 16) & 1u)) >> 16);
}
__device__ __forceinline__ uint32_t cvtpk(float lo, float hi) {
    uint32_t d;
    asm("v_cvt_pk_bf16_f32 %0, %1, %2" : "=v"(d) : "v"(lo), "v"(hi));
    return d;
}
__device__ __forceinline__ void gld_lds16(const void* g, void* l) {
    __builtin_amdgcn_global_load_lds(
        (const __attribute__((address_space(1))) unsigned int*)g,
        (__attribute__((address_space(3))) unsigned int*)l, 16, 0, 0);
}

// ---------------- Router ----------------
__global__ __launch_bounds__(256) void k_router(
    const float* __restrict__ x, const float* __restrict__ gw,
    const float* __restrict__ bias,
    int* __restrict__ counts, int* __restrict__ tids, float* __restrict__ tws)
{
    __shared__ __align__(16) float xrow[Hdim];
    __shared__ float lg[Enum];
    const int t = blockIdx.x;
    const float* xr = x + (size_t)t * Hdim;

    for (int i = threadIdx.x; i < Hdim / 4; i += 256)
        ((f32x4*)xrow)[i] = ((const f32x4*)xr)[i];
    __syncthreads();

    const int lane = threadIdx.x & 63;
    const int wid  = threadIdx.x >> 6;
    for (int e = wid; e < Enum; e += 4) {
        const float* g = gw + (size_t)e * Hdim;
        float s = 0.f;
        for (int j = lane; j < Hdim; j += 64) s += xrow[j] * g[j];
        #pragma unroll
        for (int off = 32; off; off >>= 1) s += __shfl_xor(s, off);
        if (lane == 0) lg[e] = s;
    }
    __syncthreads();

    if (threadIdx.x == 0) {
        float m = lg[0];
        #pragma unroll
        for (int e = 1; e < Enum; ++e) m = fmaxf(m, lg[e]);
        float sc[Enum]; float sum = 0.f;
        #pragma unroll
        for (int e = 0; e < Enum; ++e) { float ex = expf(lg[e] - m); sc[e] = ex; sum += ex; }
        float inv = 1.f / sum;
        #pragma unroll
        for (int e = 0; e < Enum; ++e) sc[e] *= inv;
        int i0 = 0; float b0 = sc[0] + bias[0];
        #pragma unroll
        for (int e = 1; e < Enum; ++e) { float bb = sc[e] + bias[e]; if (bb > b0) { b0 = bb; i0 = e; } }
        int i1 = -1; float b1 = -1e30f;
        #pragma unroll
        for (int e = 0; e < Enum; ++e) {
            if (e == i0) continue;
            float bb = sc[e] + bias[e]; if (bb > b1) { b1 = bb; i1 = e; }
        }
        float w0 = sc[i0], w1v = sc[i1];
        float winv = 1.f / (w0 + w1v);
        w0 *= winv; w1v *= winv;
        int p0 = atomicAdd(&counts[i0], 1);
        tids[i0 * Ttok + p0] = t; tws[i0 * Ttok + p0] = w0;
        int p1 = atomicAdd(&counts[i1], 1);
        tids[i1 * Ttok + p1] = t; tws[i1 * Ttok + p1] = w1v;
    }
}

// ---------------- Gather: compact + bf16 + tile X (fixed 256 rows/expert) ----------------
// Xg layout: [e][kg 0..255][row 0..255][8]; pad rows zero. grid (8 strips, 64 = 4c x 16e).
__global__ __launch_bounds__(256) void k_gather(
    const float* __restrict__ x, const int* __restrict__ counts,
    const int* __restrict__ tids, unsigned short* __restrict__ Xg)
{
    const int e = blockIdx.y >> 2, c = blockIdx.y & 3;
    const int Ne = counts[e];
    const int s  = blockIdx.x;          // kg strip: [s*32, s*32+32)
    const int r  = threadIdx.x & 63;
    const int kq = threadIdx.x >> 6;    // 0..3
    const int row = c * 64 + r;
    const bool valid = row < Ne;
    const int tok = valid ? tids[e * Ttok + row] : 0;
    const float* xr = x + (size_t)tok * Hdim;

    #pragma unroll
    for (int j = 0; j < 8; ++j) {
        int kg = s * 32 + j * 4 + kq;
        uint4 o = make_uint4(0, 0, 0, 0);
        if (valid) {
            f32x4 p0 = *(const f32x4*)(xr + kg * 8);
            f32x4 p1 = *(const f32x4*)(xr + kg * 8 + 4);
            o.x = cvtpk(p0[0], p0[1]); o.y = cvtpk(p0[2], p0[3]);
            o.z = cvtpk(p1[0], p1[1]); o.w = cvtpk(p1[2], p1[3]);
        }
        *(uint4*)(Xg + ((size_t)(e * 256 + kg) * 256 + row) * 8) = o;
    }
}

// ---------------- Stage 2: He = silu(X@W1)*(X@W3), gload_lds ring pipeline ----------------
// grid (16 cb, 16 e), block 512 (8 waves: wr=wid>>2, wc=wid&3). M=256, N=64(+64), BK=32.
__global__ __launch_bounds__(512, 2) void k_h(
    const unsigned short* __restrict__ Xg,
    const float* __restrict__ w1, const float* __restrict__ w3,
    unsigned short* __restrict__ He)
{
    const int e    = blockIdx.y;
    const int cb   = blockIdx.x;
    const int col0 = cb * 64;
    const int tid  = threadIdx.x;
    const int lane = tid & 63;
    const int wid  = tid >> 6;
    const int l15  = lane & 15;
    const int kq   = lane >> 4;
    const int wr   = wid >> 2, wc = wid & 3;

    __shared__ float          Wr[4][32][128];      // 64 KB fp32: [buf][krow][w1 0-63 | w3 64-127]
    __shared__ unsigned short Ar[4][4][256][8];    // 64 KB bf16: [buf][kg][row][8]

    // A pieces (2/wave): q = wid*2+qq -> kgoff q>>2, rowq q&3
    const unsigned short* asrc[2]; int aoff[2];
    #pragma unroll
    for (int qq = 0; qq < 2; ++qq) {
        int q = wid * 2 + qq;
        asrc[qq] = Xg + ((size_t)(e * 256 + (q >> 2)) * 256 + (q & 3) * 64 + lane) * 8;
        aoff[qq] = q * 1024;
    }
    // W pieces (2/wave): p = wid*2+pp -> krows {2p, 2p+1}; lanes 0-15 of half: w1, 16-31: w3
    const float* wsrcp[2]; int woff[2];
    #pragma unroll
    for (int pp = 0; pp < 2; ++pp) {
        int p  = wid * 2 + pp;
        int kr = p * 2 + (lane >> 5);
        int lc = lane & 31;
        wsrcp[pp] = (lc < 16)
            ? (w1 + ((size_t)e * Hdim + kr) * Idim + col0 + lc * 4)
            : (w3 + ((size_t)e * Hdim + kr) * Idim + col0 + (lc - 16) * 4);
        woff[pp] = p * 1024;
    }

    f32x4 acc1[8], acc3[8];
    #pragma unroll
    for (int a = 0; a < 8; ++a) { acc1[a] = (f32x4)(0.f); acc3[a] = (f32x4)(0.f); }

    char* ArB = (char*)&Ar[0][0][0][0];
    char* WrB = (char*)&Wr[0][0][0];

    auto ISSUE = [&](int s, int buf) {
        #pragma unroll
        for (int qq = 0; qq < 2; ++qq)
            gld_lds16(asrc[qq] + (size_t)s * 8192, ArB + buf * 16384 + aoff[qq]);
        #pragma unroll
        for (int pp = 0; pp < 2; ++pp)
            gld_lds16(wsrcp[pp] + (size_t)s * 32 * Idim, WrB + buf * 16384 + woff[pp]);
    };
    auto CONSUME = [&](int ri) {
        float b1f[8], b3f[8];
        #pragma unroll
        for (int j = 0; j < 8; ++j) {
            b1f[j] = Wr[ri][kq * 8 + j][wc * 16 + l15];
            b3f[j] = Wr[ri][kq * 8 + j][64 + wc * 16 + l15];
        }
        short8 b1, b3;
        uint32_t* b1u = (uint32_t*)&b1; uint32_t* b3u = (uint32_t*)&b3;
        #pragma unroll
        for (int j = 0; j < 4; ++j) {
            b1u[j] = cvtpk(b1f[2 * j], b1f[2 * j + 1]);
            b3u[j] = cvtpk(b3f[2 * j], b3f[2 * j + 1]);
        }
        #pragma unroll
        for (int fr = 0; fr < 8; ++fr) {
            short8 a = *(const short8*)&Ar[ri][kq][wr * 128 + fr * 16 + l15][0];
            acc1[fr] = __builtin_amdgcn_mfma_f32_16x16x32_bf16(a, b1, acc1[fr], 0, 0, 0);
            acc3[fr] = __builtin_amdgcn_mfma_f32_16x16x32_bf16(a, b3, acc3[fr], 0, 0, 0);
        }
    };
    auto STEP = [&](int s, int ri) {
        int s2 = s + 2 < NKH ? s + 2 : NKH - 1;
        ISSUE(s2, (ri + 2) & 3);
        asm volatile("s_waitcnt vmcnt(8)" ::: "memory");
        __builtin_amdgcn_s_barrier();
        CONSUME(ri);
    };

    ISSUE(0, 0); ISSUE(1, 1);
    for (int i = 0; i < NKH; i += 4) {
        STEP(i, 0); STEP(i + 1, 1); STEP(i + 2, 2); STEP(i + 3, 3);
    }
    asm volatile("s_waitcnt vmcnt(0)" ::: "memory");

    // epilogue: he = silu(h1)*h3 in fp32 regs -> He tiled [e][kg][row][8]
    const int colh = col0 + wc * 16 + l15;
    unsigned short* Hc = He + ((size_t)(e * 128 + (colh >> 3)) * 256) * 8 + (colh & 7);
    #pragma unroll
    for (int fr = 0; fr < 8; ++fr) {
        int rbase = wr * 128 + fr * 16 + kq * 4;
        #pragma unroll
        for (int k = 0; k < 4; ++k) {
            float h1 = acc1[fr][k], h3 = acc3[fr][k];
            float he = h1 * h3 * __builtin_amdgcn_rcpf(1.f + __expf(-h1));
            Hc[(size_t)(rbase + k) * 8] = f2bf(he);
        }
    }
}

// ---------------- Stage 3: out += w * (He @ W2), gload_lds ring pipeline ----------------
// grid (16 cb, 16 e), block 512. M=256, N=128, BK=32, NK=32.
__global__ __launch_bounds__(512, 2) void k_o(
    const unsigned short* __restrict__ He,
    const float* __restrict__ w2,
    const int* __restrict__ counts, const int* __restrict__ tids,
    const float* __restrict__ tws,
    float* __restrict__ out)
{
    const int e    = blockIdx.y;
    const int Ne   = counts[e];
    const int col0 = blockIdx.x * 128;
    const int tid  = threadIdx.x;
    const int lane = tid & 63;
    const int wid  = tid >> 6;
    const int l15  = lane & 15;
    const int kq   = lane >> 4;
    const int wr   = wid >> 2, wc = wid & 3;

    __shared__ float          Wr[4][32][128];      // 64 KB fp32
    __shared__ unsigned short Ar[4][4][256][8];    // 64 KB bf16

    const unsigned short* asrc[2]; int aoff[2];
    #pragma unroll
    for (int qq = 0; qq < 2; ++qq) {
        int q = wid * 2 + qq;
        asrc[qq] = He + ((size_t)(e * 128 + (q >> 2)) * 256 + (q & 3) * 64 + lane) * 8;
        aoff[qq] = q * 1024;
    }
    const float* wsrcp[2]; int woff[2];
    #pragma unroll
    for (int pp = 0; pp < 2; ++pp) {
        int p  = wid * 2 + pp;
        int kr = p * 2 + (lane >> 5);
        int lc = lane & 31;
        wsrcp[pp] = w2 + ((size_t)e * Idim + kr) * Hdim + col0 + lc * 4;
        woff[pp] = p * 1024;
    }

    f32x4 acc[8][2];
    #pragma unroll
    for (int a = 0; a < 8; ++a) { acc[a][0] = (f32x4)(0.f); acc[a][1] = (f32x4)(0.f); }

    char* ArB = (char*)&Ar[0][0][0][0];
    char* WrB = (char*)&Wr[0][0][0];

    auto ISSUE = [&](int s, int buf) {
        #pragma unroll
        for (int qq = 0; qq < 2; ++qq)
            gld_lds16(asrc[qq] + (size_t)s * 8192, ArB + buf * 16384 + aoff[qq]);
        #pragma unroll
        for (int pp = 0; pp < 2; ++pp)
            gld_lds16(wsrcp[pp] + (size_t)s * 32 * Hdim, WrB + buf * 16384 + woff[pp]);
    };
    auto CONSUME = [&](int ri) {
        float bf[2][8];
        #pragma unroll
        for (int fc = 0; fc < 2; ++fc)
            #pragma unroll
            for (int j = 0; j < 8; ++j)
                bf[fc][j] = Wr[ri][kq * 8 + j][wc * 32 + fc * 16 + l15];
        short8 b[2];
        #pragma unroll
        for (int fc = 0; fc < 2; ++fc) {
            uint32_t* bu = (uint32_t*)&b[fc];
            #pragma unroll
            for (int j = 0; j < 4; ++j)
                bu[j] = cvtpk(bf[fc][2 * j], bf[fc][2 * j + 1]);
        }
        #pragma unroll
        for (int fr = 0; fr < 8; ++fr) {
            short8 a = *(const short8*)&Ar[ri][kq][wr * 128 + fr * 16 + l15][0];
            acc[fr][0] = __builtin_amdgcn_mfma_f32_16x16x32_bf16(a, b[0], acc[fr][0], 0, 0, 0);
            acc[fr][1] = __builtin_amdgcn_mfma_f32_16x16x32_bf16(a, b[1], acc[fr][1], 0, 0, 0);
        }
    };
    auto STEP = [&](int s, int ri) {
        int s2 = s + 2 < NKO ? s + 2 : NKO - 1;
        ISSUE(s2, (ri + 2) & 3);
        asm volatile("s_waitcnt vmcnt(8)" ::: "memory");
        __builtin_amdgcn_s_barrier();
        CONSUME(ri);
    };

    ISSUE(0, 0); ISSUE(1, 1);
    for (int i = 0; i < NKO; i += 4) {
        STEP(i, 0); STEP(i + 1, 1); STEP(i + 2, 2); STEP(i + 3, 3);
    }
    asm volatile("s_waitcnt vmcnt(0)" ::: "memory");

    #pragma unroll
    for (int fr = 0; fr < 8; ++fr) {
        #pragma unroll
        for (int k = 0; k < 4; ++k) {
            int grow = wr * 128 + fr * 16 + kq * 4 + k;
            if (grow < Ne) {
                int   tk = tids[e * Ttok + grow];
                float w  = tws[e * Ttok + grow];
                #pragma unroll
                for (int fc = 0; fc < 2; ++fc)
                    atomicAdd(&out[(size_t)tk * Hdim + col0 + wc * 32 + fc * 16 + l15],
                              w * acc[fr][fc][k]);
            }
        }
    }
}

extern "C" void kernel_launch(void* const* d_in, const int* in_sizes, int n_in,
                              void* d_out, int out_size, void* d_ws, size_t ws_size,
                              hipStream_t stream)
{
    const float* x    = (const float*)d_in[0];
    const float* gw   = (const float*)d_in[1];
    const float* bias = (const float*)d_in[2];
    const float* w1   = (const float*)d_in[3];
    const float* w3   = (const float*)d_in[4];
    const float* w2   = (const float*)d_in[5];
    float* out = (float*)d_out;

    char* ws = (char*)d_ws;
    int*            counts = (int*)ws;                         // @0        64 B
    int*            tids   = (int*)(ws + 1024);                // 64 KB
    float*          tws    = (float*)(ws + 66560);             // 64 KB
    unsigned short* Xg     = (unsigned short*)(ws + 132096);   // 16.78 MB [e][256kg][256r][8]
    unsigned short* He     = (unsigned short*)(ws + 16909312); // 8.39 MB  [e][128kg][256r][8]

    hipMemsetAsync(counts, 0, Enum * sizeof(int), stream);
    hipMemsetAsync(out, 0, (size_t)Ttok * Hdim * sizeof(float), stream);

    k_router<<<dim3(Ttok), dim3(256), 0, stream>>>(x, gw, bias, counts, tids, tws);
    k_gather<<<dim3(8, 64), dim3(256), 0, stream>>>(x, counts, tids, Xg);
    k_h<<<dim3(16, Enum), dim3(512), 0, stream>>>(Xg, w1, w3, He);
    k_o<<<dim3(16, Enum), dim3(512), 0, stream>>>(He, w2, counts, tids, tws, out);
}